// Round 15
// baseline (691.049 us; speedup 1.0000x reference)
//
#include <hip/hip_runtime.h>

// LightGCN: pull-CSR SpMM with int8 row-quantized sources (128 B/row = 1 line
// + per-row fp32 scale), atomic-free counting-sort CSR build.
// R15: fix R14's misaligned uint4 CSR loads — bucket output base is now
// rounded to a 4-entry (16 B) boundary, so padded row segments are truly
// dwordx4-aligned. PAD 192->196 (3 alignment slip + 192 row pads).
// Build entry (uint2): x = dstLocal12 << 18 | src18, y = fp32 weight bits.
// Final CSR entry (u32): wq14 << 18 | src18, weight = wq/16384.
// Padded combined row space: [0,U) users, [UA,UA+I) items, UA=roundup(U,64).

#define D 128
#define CHUNK 8192
#define CTILE 64
#define SRCMASK 0x3FFFF
#define TPB 256
#define RS_CAP 6144
#define NSPLIT 16
#define PAD 196   // per-bucket slack: <=3 align slip + 64 rows * 3 pad

typedef unsigned int u32x2 __attribute__((ext_vector_type(2)));
typedef float f32x4 __attribute__((ext_vector_type(4)));

__device__ inline uint2 ntload_u2(const uint2* p) {
    u32x2 v = __builtin_nontemporal_load((const u32x2*)p);
    uint2 r; r.x = v.x; r.y = v.y; return r;
}
__device__ inline void ntstore_f4(float* p, float4 v) {
    f32x4 t; t.x = v.x; t.y = v.y; t.z = v.z; t.w = v.w;
    __builtin_nontemporal_store(t, (f32x4*)p);
}
__device__ inline int ntload_i(const int* p) { return __builtin_nontemporal_load(p); }
__device__ inline float ntload_f(const float* p) { return __builtin_nontemporal_load(p); }
__device__ inline float4 ntload_f4(const float* p) {
    f32x4 v = __builtin_nontemporal_load((const f32x4*)p);
    return make_float4(v.x, v.y, v.z, v.w);
}

// ---------- excess-128 int8 helpers ----------
__device__ inline unsigned pack4(float a, float b, float c, float d, float qs) {
    int q0 = __float2int_rn(fmaf(a, qs, 128.f)), q1 = __float2int_rn(fmaf(b, qs, 128.f));
    int q2 = __float2int_rn(fmaf(c, qs, 128.f)), q3 = __float2int_rn(fmaf(d, qs, 128.f));
    return ((unsigned)(q0 & 255)) | ((unsigned)(q1 & 255) << 8) |
           ((unsigned)(q2 & 255) << 16) | ((unsigned)(q3 & 255) << 24);
}

__device__ inline void acc_u8(float4& sa, float4& sb, uint2 raw, float f, float& F) {
    unsigned x = raw.x, y = raw.y;
    sa.x = fmaf(f, (float)(x & 255u),         sa.x);
    sa.y = fmaf(f, (float)((x >> 8) & 255u),  sa.y);
    sa.z = fmaf(f, (float)((x >> 16) & 255u), sa.z);
    sa.w = fmaf(f, (float)(x >> 24),          sa.w);
    sb.x = fmaf(f, (float)(y & 255u),         sb.x);
    sb.y = fmaf(f, (float)((y >> 8) & 255u),  sb.y);
    sb.z = fmaf(f, (float)((y >> 16) & 255u), sb.z);
    sb.w = fmaf(f, (float)(y >> 24),          sb.w);
    F += f;
}

// ---------- quantize fp32 inputs -> excess-128 int8 rows + per-row scale ----------
__global__ __launch_bounds__(TPB) void k_quant8(
    const float* __restrict__ ue, const float* __restrict__ ie,
    uint2* __restrict__ h0q, float* __restrict__ sc0, int U, int UA, int NP) {
    int row = blockIdx.x * (TPB / 16) + (threadIdx.x >> 4);
    if (row >= NP) return;
    int lane = threadIdx.x & 15;
    float4 a = make_float4(0.f, 0.f, 0.f, 0.f);
    float4 b = make_float4(0.f, 0.f, 0.f, 0.f);
    const float* p = nullptr;
    if (row < U)        p = ue + (size_t)row * D + lane * 8;
    else if (row >= UA) p = ie + (size_t)(row - UA) * D + lane * 8;
    if (p) { a = ntload_f4(p); b = ntload_f4(p + 4); }
    float m = fmaxf(fmaxf(fmaxf(fabsf(a.x), fabsf(a.y)), fmaxf(fabsf(a.z), fabsf(a.w))),
                    fmaxf(fmaxf(fabsf(b.x), fabsf(b.y)), fmaxf(fabsf(b.z), fabsf(b.w))));
    for (int d_ = 1; d_ < 16; d_ <<= 1) m = fmaxf(m, __shfl_xor(m, d_));
    float qs = (m > 0.f) ? 127.f / m : 0.f;
    uint2 q;
    q.x = pack4(a.x, a.y, a.z, a.w, qs);
    q.y = pack4(b.x, b.y, b.z, b.w, qs);
    h0q[(size_t)row * 16 + lane] = q;
    if (lane == 0) sc0[row] = m * (1.f / 127.f);
}

// ---------- per-chunk bucket histogram -> C[c][b], super-bucket -> C2[c][s] ----------
__global__ __launch_bounds__(256) void k_count(const int* __restrict__ eu,
                                               const int* __restrict__ ei,
                                               int* __restrict__ C, int* __restrict__ C2,
                                               int E, int NB, int NS, int UA) {
    extern __shared__ int hist[];
    for (int k = threadIdx.x; k < NB; k += blockDim.x) hist[k] = 0;
    __syncthreads();
    int base = blockIdx.x * CHUNK;
    int n = min(CHUNK, E - base);
    for (int t = threadIdx.x; t < n; t += blockDim.x) {
        int u = ntload_i(eu + base + t);
        int i = ntload_i(ei + base + t);
        atomicAdd(&hist[u >> 6], 1);
        atomicAdd(&hist[(UA + i) >> 6], 1);
    }
    __syncthreads();
    int* Crow = C + (size_t)blockIdx.x * NB;
    for (int k = threadIdx.x; k < NB; k += blockDim.x) Crow[k] = hist[k];
    int* C2row = C2 + (size_t)blockIdx.x * NS;
    for (int s = threadIdx.x; s < NS; s += blockDim.x) {
        int b0 = s * 64, b1 = min(b0 + 64, NB);
        int acc = 0;
        for (int b = b0; b < b1; ++b) acc += hist[b];
        C2row[s] = acc;
    }
}

// ---------- tiled column scans over C (NC x NB) ----------
__global__ __launch_bounds__(256) void k_tile_sum(const int* __restrict__ C,
                                                  int* __restrict__ S, int NB, int NC) {
    int b = blockIdx.x * 256 + threadIdx.x;
    if (b >= NB) return;
    int tc = blockIdx.y;
    int c0 = tc * CTILE, c1 = min(c0 + CTILE, NC);
    int s = 0;
    for (int c = c0; c < c1; ++c) s += C[(size_t)c * NB + b];
    S[(size_t)tc * NB + b] = s;
}

__global__ __launch_bounds__(256) void k_super(int* __restrict__ S, int* __restrict__ T,
                                               int NB, int TC) {
    int b = blockIdx.x * 256 + threadIdx.x;
    if (b >= NB) return;
    int run = 0;
    for (int tc = 0; tc < TC; ++tc) {
        size_t k = (size_t)tc * NB + b;
        int v = S[k];
        S[k] = run;
        run += v;
    }
    T[b] = run;
}

__global__ __launch_bounds__(1024) void k_scan(const int* __restrict__ T,
                                               int* __restrict__ offb, int N) {
    __shared__ int partial[1024];
    int t = threadIdx.x;
    int CH = (N + 1023) >> 10;
    int c0 = min(t * CH, N), c1 = min(c0 + CH, N);
    int sum = 0;
    for (int k = c0; k < c1; ++k) sum += T[k];
    partial[t] = sum;
    __syncthreads();
    for (int s = 1; s < 1024; s <<= 1) {
        int add = (t >= s) ? partial[t - s] : 0;
        __syncthreads();
        partial[t] += add;
        __syncthreads();
    }
    int run = (t == 0) ? 0 : partial[t - 1];
    for (int k = c0; k < c1; ++k) { offb[k] = run; run += T[k]; }
    if (t == 0) offb[N] = partial[1023];
}

__global__ __launch_bounds__(256) void k_colscan(const int* __restrict__ C,
                                                 const int* __restrict__ S,
                                                 const int* __restrict__ offb,
                                                 int* __restrict__ colScan, int NB, int NC) {
    int b = blockIdx.x * 256 + threadIdx.x;
    if (b >= NB) return;
    int tc = blockIdx.y;
    int c0 = tc * CTILE, c1 = min(c0 + CTILE, NC);
    int run = offb[b] + S[(size_t)tc * NB + b];
    for (int c = c0; c < c1; ++c) {
        size_t k = (size_t)c * NB + b;
        colScan[k] = run;
        run += C[k];
    }
}

// ---------- pass 1: partition entries into super-buckets, chunk-local dense ----------
__global__ __launch_bounds__(256) void k_split(
    const int* __restrict__ eu, const int* __restrict__ ei, const float* __restrict__ w,
    const int* __restrict__ C2, int* __restrict__ P2, uint2* __restrict__ sbA,
    int E, int NC, int NS, int UA) {
    __shared__ int cur[64];
    __shared__ int tmp[64];
    int t = threadIdx.x;
    int c = blockIdx.x;
    if (c >= NC) return;
    if (t < NS) tmp[t] = C2[(size_t)c * NS + t];
    __syncthreads();
    if (t == 0) {
        int run = c * 2 * CHUNK;
        for (int s = 0; s < NS; ++s) {
            int v = tmp[s];
            cur[s] = run;
            P2[(size_t)c * NS + s] = run;
            run += v;
        }
    }
    __syncthreads();
    int base = c * CHUNK;
    int n = min(CHUNK, E - base);
    for (int k = t; k < n; k += 256) {
        int u  = ntload_i(eu + base + k);
        int gi = UA + ntload_i(ei + base + k);
        unsigned wb = __float_as_uint(ntload_f(w + base + k));
        int pu = atomicAdd(&cur[u >> 12], 1);
        sbA[pu] = make_uint2(((unsigned)(u & 4095) << 18) | (unsigned)gi, wb);
        int pi = atomicAdd(&cur[gi >> 12], 1);
        sbA[pi] = make_uint2(((unsigned)(gi & 4095) << 18) | (unsigned)u, wb);
    }
}

// ---------- pass 2: super-bucket runs -> final bucket-grouped positions ----------
__global__ __launch_bounds__(256) void k_sbscatter(
    const uint2* __restrict__ sbA, uint2* __restrict__ bkt,
    const int* __restrict__ C2, const int* __restrict__ P2,
    const int* __restrict__ colScan, int NB, int NC, int NS) {
    __shared__ int cur[64];
    int s = blockIdx.y;
    int j = blockIdx.x;
    int CL = (NC + NSPLIT - 1) / NSPLIT;
    int c0 = j * CL, c1 = min(NC, c0 + CL);
    if (c0 >= c1) return;
    int t = threadIdx.x;
    int b0 = s * 64;
    int nb = min(64, NB - b0);
    if (t < nb) cur[t] = colScan[(size_t)c0 * NB + b0 + t];
    __syncthreads();
    for (int c = c0; c < c1; ++c) {
        int start = P2[(size_t)c * NS + s];
        int len   = C2[(size_t)c * NS + s];
        for (int k = t; k < len; k += 256) {
            uint2 e = ntload_u2(sbA + start + k);
            int bl = (int)((e.x >> 24) & 63u);
            int p = atomicAdd(&cur[bl], 1);
            bkt[p] = e;
        }
    }
}

// ---------- per-bucket counting sort by row -> 16B-aligned row-grouped u32 CSR ----
// Output entry: wq14 << 18 | src18 (weight = wq / 16384). Row slots padded to
// multiple of 4 with 0-entries; bucket out base = align4(offb[b]) + PAD*b.
__device__ inline unsigned pack_entry(uint2 e) {
    float wv = __uint_as_float(e.y);
    int wq = __float2int_rn(wv * 16384.f);
    wq = min(wq, 16383);
    wq = max(wq, 0);
    return (e.x & 0x3FFFFu) | ((unsigned)wq << 18);
}

__global__ __launch_bounds__(256) void k_rowsort(
    const uint2* __restrict__ entA, unsigned* __restrict__ entB,
    const int* __restrict__ offb, int* __restrict__ off, int NP, int NB) {
    __shared__ int hist[64];
    __shared__ int rowOff[64];
    __shared__ int cursor[64];
    __shared__ int padTot;
    __shared__ uint2 ebuf[RS_CAP];
    int b = blockIdx.x, t = threadIdx.x;
    int segBase = offb[b];
    int len = offb[b + 1] - segBase;
    int outBase = ((segBase + 3) & ~3) + PAD * b;          // 16B-aligned
    if (t < 64) hist[t] = 0;
    __syncthreads();
    bool inLds = (len <= RS_CAP);
    for (int k = t; k < len; k += 256) {
        uint2 e = ntload_u2(entA + segBase + k);
        if (inLds) ebuf[k] = e;
        atomicAdd(&hist[(e.x >> 18) & 63u], 1);
    }
    __syncthreads();
    if (t == 0) {
        int run = 0;
        for (int r = 0; r < 64; ++r) {
            rowOff[r] = run; cursor[r] = run;
            run += (hist[r] + 3) & ~3;
        }
        padTot = run;
    }
    __syncthreads();
    if (inLds) {
        for (int k = t; k < len; k += 256) {
            uint2 e = ebuf[k];
            int p = atomicAdd(&cursor[(e.x >> 18) & 63u], 1);
            entB[outBase + p] = pack_entry(e);
        }
    } else {
        for (int k = t; k < len; k += 256) {
            uint2 e = ntload_u2(entA + segBase + k);
            int p = atomicAdd(&cursor[(e.x >> 18) & 63u], 1);
            entB[outBase + p] = pack_entry(e);
        }
    }
    __syncthreads();
    // fill row-tail pads (<=3 per row)
    if (t < 64) {
        int start = rowOff[t] + hist[t];
        int end_  = rowOff[t] + ((hist[t] + 3) & ~3);
        for (int k = start; k < end_; ++k) entB[outBase + k] = 0u;
    }
    // fill inter-bucket gap up to next bucket's outBase
    int nextBase = ((offb[b + 1] + 3) & ~3) + PAD * (b + 1);
    for (int k = outBase + padTot + t; k < nextBase; k += 256) entB[k] = 0u;
    if (t < 64) {
        int g = b * 64 + t;
        if (g <= NP) off[g] = outBase + rowOff[t];
    }
    if (b == NB - 1 && t == 0 && NP == NB * 64) off[NP] = outBase + padTot;
}

// ---------- pull-SpMM on excess-128 int8 sources (phase-split) ----------
// CSR entry: wq14 << 18 | src18, 16B-aligned 4-entry rows. MODE 0: quantize
// -> nxtq+scn. MODE 1: fused epilogue to fp32 out.
#define WDEQ (1.f / 16384.f)
template <int MODE>
__global__ __launch_bounds__(TPB) void k_spmm(
    const uint2* __restrict__ q, const float* __restrict__ sc,
    uint2* __restrict__ nxtq, float* __restrict__ scn,
    const uint2* __restrict__ e1q, const float* __restrict__ sc1,
    const uint2* __restrict__ e2q, const float* __restrict__ sc2,
    const float* __restrict__ ue, const float* __restrict__ ie,
    float* __restrict__ out,
    const int* __restrict__ off, const unsigned* __restrict__ csr,
    int U, int UA, int rowBase, int rowCnt) {
    int row = rowBase + blockIdx.x * (TPB / 16) + (threadIdx.x >> 4);
    if (row >= rowBase + rowCnt) return;
    int lane = threadIdx.x & 15;
    int beg = off[row], end = off[row + 1];
    float4 sa = make_float4(0.f, 0.f, 0.f, 0.f);
    float4 sb = make_float4(0.f, 0.f, 0.f, 0.f);
    float F = 0.f;

    int n4 = (end - beg) >> 2;           // rows are 4-aligned: no tail
    const uint4* cp = (const uint4*)(csr + beg);
    if (n4 > 0) {
        uint4 e = cp[0];
        for (int it = 0; it < n4; ++it) {
            unsigned m0 = e.x, m1 = e.y, m2 = e.z, m3 = e.w;
            int s0 = m0 & SRCMASK, s1 = m1 & SRCMASK;
            int s2 = m2 & SRCMASK, s3 = m3 & SRCMASK;
            uint2 g0 = q[(size_t)s0 * 16 + lane];
            uint2 g1 = q[(size_t)s1 * 16 + lane];
            uint2 g2 = q[(size_t)s2 * 16 + lane];
            uint2 g3 = q[(size_t)s3 * 16 + lane];
            float f0 = (float)(m0 >> 18) * WDEQ * sc[s0];
            float f1 = (float)(m1 >> 18) * WDEQ * sc[s1];
            float f2 = (float)(m2 >> 18) * WDEQ * sc[s2];
            float f3 = (float)(m3 >> 18) * WDEQ * sc[s3];
            e = cp[min(it + 1, n4 - 1)];  // prefetch next entry vector
            acc_u8(sa, sb, g0, f0, F);
            acc_u8(sa, sb, g1, f1, F);
            acc_u8(sa, sb, g2, f2, F);
            acc_u8(sa, sb, g3, f3, F);
        }
    }
    // excess-128 correction: value = b - 128
    float c128 = 128.f * F;
    sa.x -= c128; sa.y -= c128; sa.z -= c128; sa.w -= c128;
    sb.x -= c128; sb.y -= c128; sb.z -= c128; sb.w -= c128;

    if (MODE == 0) {
        float m = fmaxf(fmaxf(fmaxf(fabsf(sa.x), fabsf(sa.y)), fmaxf(fabsf(sa.z), fabsf(sa.w))),
                        fmaxf(fmaxf(fabsf(sb.x), fabsf(sb.y)), fmaxf(fabsf(sb.z), fabsf(sb.w))));
        for (int d_ = 1; d_ < 16; d_ <<= 1) m = fmaxf(m, __shfl_xor(m, d_));
        float qs = (m > 0.f) ? 127.f / m : 0.f;
        uint2 qo;
        qo.x = pack4(sa.x, sa.y, sa.z, sa.w, qs);
        qo.y = pack4(sb.x, sb.y, sb.z, sb.w, qs);
        nxtq[(size_t)row * 16 + lane] = qo;   // re-read as gather source: cached
        if (lane == 0) scn[row] = m * (1.f / 127.f);
    } else {
        int outRow;
        const float* e0p;
        if (row < U)        { outRow = row;            e0p = ue + (size_t)row * D + lane * 8; }
        else if (row >= UA) { outRow = U + (row - UA); e0p = ie + (size_t)(row - UA) * D + lane * 8; }
        else return;  // pad row
        float4 e0a = ntload_f4(e0p);
        float4 e0b = ntload_f4(e0p + 4);
        uint2 q1 = e1q[(size_t)row * 16 + lane]; float s1r = sc1[row];
        uint2 q2 = e2q[(size_t)row * 16 + lane]; float s2r = sc2[row];
        unsigned x1 = q1.x, y1 = q1.y, x2 = q2.x, y2 = q2.y;
        float4 ra, rb;
        ra.x = 0.25f * (e0a.x + s1r * ((float)(x1 & 255u) - 128.f)         + s2r * ((float)(x2 & 255u) - 128.f)         + sa.x);
        ra.y = 0.25f * (e0a.y + s1r * ((float)((x1 >> 8) & 255u) - 128.f)  + s2r * ((float)((x2 >> 8) & 255u) - 128.f)  + sa.y);
        ra.z = 0.25f * (e0a.z + s1r * ((float)((x1 >> 16) & 255u) - 128.f) + s2r * ((float)((x2 >> 16) & 255u) - 128.f) + sa.z);
        ra.w = 0.25f * (e0a.w + s1r * ((float)(x1 >> 24) - 128.f)          + s2r * ((float)(x2 >> 24) - 128.f)          + sa.w);
        rb.x = 0.25f * (e0b.x + s1r * ((float)(y1 & 255u) - 128.f)         + s2r * ((float)(y2 & 255u) - 128.f)         + sb.x);
        rb.y = 0.25f * (e0b.y + s1r * ((float)((y1 >> 8) & 255u) - 128.f)  + s2r * ((float)((y2 >> 8) & 255u) - 128.f)  + sb.y);
        rb.z = 0.25f * (e0b.z + s1r * ((float)((y1 >> 16) & 255u) - 128.f) + s2r * ((float)((y2 >> 16) & 255u) - 128.f) + sb.z);
        rb.w = 0.25f * (e0b.w + s1r * ((float)(y1 >> 24) - 128.f)          + s2r * ((float)(y2 >> 24) - 128.f)          + sb.w);
        float* op = out + (size_t)outRow * D + lane * 8;
        ntstore_f4(op, ra);
        ntstore_f4(op + 4, rb);
    }
}

extern "C" void kernel_launch(void* const* d_in, const int* in_sizes, int n_in,
                              void* d_out, int out_size, void* d_ws, size_t ws_size,
                              hipStream_t stream) {
    const float* ue = (const float*)d_in[0];
    const float* ie = (const float*)d_in[1];
    const float* w  = (const float*)d_in[2];
    const int*   eu = (const int*)d_in[3];
    const int*   ei = (const int*)d_in[4];
    // n_layers fixed at 3 by the reference setup.

    const int U  = in_sizes[0] / D;
    const int I  = in_sizes[1] / D;
    const int E  = in_sizes[2];
    const int UA = ((U + 63) >> 6) << 6;
    const int NP = UA + I;
    const int NB = (NP + 63) >> 6;
    const int NS = (NP + 4095) >> 12;       // super-buckets (4096 rows)
    const int NC = (E + CHUNK - 1) / CHUNK;
    const int TC = (NC + CTILE - 1) / CTILE;
    const size_t nE2 = (size_t)2 * E;
    const size_t nX  = (size_t)NC * 2 * CHUNK;   // sbA region (>= nE2)

    if (NS > 64) return;  // geometry guard

    // ws: h0q | e1q | e2q | sc0..2 | X(sbA / u32 CSR) | Y(bkt) | C | colScan | S | T
    //     | offb | off | C2 | P2
    uint2* h0q = (uint2*)d_ws;
    uint2* e1q = h0q + (size_t)NP * 16;
    uint2* e2q = e1q + (size_t)NP * 16;
    float* sc0 = (float*)(e2q + (size_t)NP * 16);
    float* sc1 = sc0 + NP;
    float* sc2 = sc1 + NP;
    uint2* X   = (uint2*)(sc2 + NP);       // pass-1 out; rowsort writes u32 CSR here
    uint2* Y   = X + nX;                   // pass-2 out (bucket-grouped)
    int* C       = (int*)(Y + nE2);
    int* colScan = C + (size_t)NC * NB;
    int* S       = colScan + (size_t)NC * NB;
    int* T       = S + (size_t)TC * NB;
    int* offb    = T + NB;
    int* off     = offb + NB + 1;
    int* C2      = off + NP + 1;
    int* P2      = C2 + (size_t)NC * NS;

    const size_t needed = (size_t)NP * D * 3 + (size_t)NP * 12
                        + (nX + nE2) * 8
                        + ((size_t)2 * NC * NB + (size_t)TC * NB + NB + (NB + 1)
                           + (NP + 1) + (size_t)2 * NC * NS) * 4;
    if (ws_size < needed) return;
    // u32 CSR (nE2 + (PAD+3)*NB entries, 4 B each) fits in X (nX uint2 slots)

    const int nbR = (NP + 15) / 16;
    const int nbU = (UA + 15) / 16;
    const int nbI = (I + 15) / 16;
    const int TB = (NB + 255) / 256;

    k_quant8<<<nbR, TPB, 0, stream>>>(ue, ie, h0q, sc0, U, UA, NP);
    k_count<<<NC, 256, (size_t)NB * 4, stream>>>(eu, ei, C, C2, E, NB, NS, UA);
    k_tile_sum<<<dim3(TB, TC), 256, 0, stream>>>(C, S, NB, NC);
    k_super<<<TB, 256, 0, stream>>>(S, T, NB, TC);
    k_scan<<<1, 1024, 0, stream>>>(T, offb, NB);
    k_colscan<<<dim3(TB, TC), 256, 0, stream>>>(C, S, offb, colScan, NB, NC);
    k_split<<<NC, 256, 0, stream>>>(eu, ei, w, C2, P2, X, E, NC, NS, UA);
    k_sbscatter<<<dim3(NSPLIT, NS), 256, 0, stream>>>(X, Y, C2, P2, colScan, NB, NC, NS);
    k_rowsort<<<NB, 256, 0, stream>>>(Y, (unsigned*)X, offb, off, NP, NB);

    const unsigned* csr = (const unsigned*)X;
    // layer 1
    k_spmm<0><<<nbU, TPB, 0, stream>>>(h0q, sc0, e1q, sc1, nullptr, nullptr, nullptr, nullptr,
                                       ue, ie, nullptr, off, csr, U, UA, 0, UA);
    k_spmm<0><<<nbI, TPB, 0, stream>>>(h0q, sc0, e1q, sc1, nullptr, nullptr, nullptr, nullptr,
                                       ue, ie, nullptr, off, csr, U, UA, UA, I);
    // layer 2
    k_spmm<0><<<nbU, TPB, 0, stream>>>(e1q, sc1, e2q, sc2, nullptr, nullptr, nullptr, nullptr,
                                       ue, ie, nullptr, off, csr, U, UA, 0, UA);
    k_spmm<0><<<nbI, TPB, 0, stream>>>(e1q, sc1, e2q, sc2, nullptr, nullptr, nullptr, nullptr,
                                       ue, ie, nullptr, off, csr, U, UA, UA, I);
    // layer 3 + fused epilogue
    k_spmm<1><<<nbU, TPB, 0, stream>>>(e2q, sc2, nullptr, nullptr, e1q, sc1, e2q, sc2,
                                       ue, ie, (float*)d_out, off, csr, U, UA, 0, UA);
    k_spmm<1><<<nbI, TPB, 0, stream>>>(e2q, sc2, nullptr, nullptr, e1q, sc1, e2q, sc2,
                                       ue, ie, (float*)d_out, off, csr, U, UA, UA, I);
}

// Round 16
// 567.481 us; speedup vs baseline: 1.2177x; 1.2177x over previous
//
#include <hip/hip_runtime.h>

// LightGCN: pull-CSR SpMM with int8 row-quantized sources (128 B/row = 1 line
// + per-row fp32 scale), atomic-free counting-sort CSR build.
// R16: exact R12 restore (its spmm measured 78us vs R14/R15's 105+) plus an
// 8-way unrolled gather loop: 8 independent row-gathers in flight per
// 16-lane group (R12 had 4). R12 ran at 2.6 TB/s miss traffic while R5/R6
// proved 3.4-3.8 TB/s is achievable -> latency-bound, MLP is the lever.
// Build entry (uint2): x = dstLocal12 << 18 | src18, y = fp32 weight bits.
// Final CSR entry (u32): wq14 << 18 | src18, weight = wq/16384.
// Padded combined row space: [0,U) users, [UA,UA+I) items, UA=roundup(U,64).

#define D 128
#define CHUNK 8192
#define CTILE 64
#define SRCMASK 0x3FFFF
#define TPB 256
#define RS_CAP 6144
#define NSPLIT 16

typedef unsigned int u32x2 __attribute__((ext_vector_type(2)));
typedef float f32x4 __attribute__((ext_vector_type(4)));

__device__ inline uint2 ntload_u2(const uint2* p) {
    u32x2 v = __builtin_nontemporal_load((const u32x2*)p);
    uint2 r; r.x = v.x; r.y = v.y; return r;
}
__device__ inline void ntstore_f4(float* p, float4 v) {
    f32x4 t; t.x = v.x; t.y = v.y; t.z = v.z; t.w = v.w;
    __builtin_nontemporal_store(t, (f32x4*)p);
}
__device__ inline int ntload_i(const int* p) { return __builtin_nontemporal_load(p); }
__device__ inline float ntload_f(const float* p) { return __builtin_nontemporal_load(p); }
__device__ inline float4 ntload_f4(const float* p) {
    f32x4 v = __builtin_nontemporal_load((const f32x4*)p);
    return make_float4(v.x, v.y, v.z, v.w);
}

// ---------- int8 helpers (signed, R12 form) ----------
__device__ inline unsigned pack4(float a, float b, float c, float d, float qs) {
    int q0 = __float2int_rn(a * qs), q1 = __float2int_rn(b * qs);
    int q2 = __float2int_rn(c * qs), q3 = __float2int_rn(d * qs);
    return ((unsigned)(q0 & 255)) | ((unsigned)(q1 & 255) << 8) |
           ((unsigned)(q2 & 255) << 16) | ((unsigned)(q3 & 255) << 24);
}

__device__ inline void acc_q8(float4& sa, float4& sb, uint2 raw, float m) {
    unsigned x = raw.x, y = raw.y;
    sa.x += m * (float)((int)(x << 24) >> 24);
    sa.y += m * (float)((int)(x << 16) >> 24);
    sa.z += m * (float)((int)(x <<  8) >> 24);
    sa.w += m * (float)((int)(x      ) >> 24);
    sb.x += m * (float)((int)(y << 24) >> 24);
    sb.y += m * (float)((int)(y << 16) >> 24);
    sb.z += m * (float)((int)(y <<  8) >> 24);
    sb.w += m * (float)((int)(y      ) >> 24);
}

// ---------- quantize fp32 inputs -> int8 rows + per-row scale ----------
__global__ __launch_bounds__(TPB) void k_quant8(
    const float* __restrict__ ue, const float* __restrict__ ie,
    uint2* __restrict__ h0q, float* __restrict__ sc0, int U, int UA, int NP) {
    int row = blockIdx.x * (TPB / 16) + (threadIdx.x >> 4);
    if (row >= NP) return;
    int lane = threadIdx.x & 15;
    float4 a = make_float4(0.f, 0.f, 0.f, 0.f);
    float4 b = make_float4(0.f, 0.f, 0.f, 0.f);
    const float* p = nullptr;
    if (row < U)        p = ue + (size_t)row * D + lane * 8;
    else if (row >= UA) p = ie + (size_t)(row - UA) * D + lane * 8;
    if (p) { a = ntload_f4(p); b = ntload_f4(p + 4); }
    float m = fmaxf(fmaxf(fmaxf(fabsf(a.x), fabsf(a.y)), fmaxf(fabsf(a.z), fabsf(a.w))),
                    fmaxf(fmaxf(fabsf(b.x), fabsf(b.y)), fmaxf(fabsf(b.z), fabsf(b.w))));
    for (int d_ = 1; d_ < 16; d_ <<= 1) m = fmaxf(m, __shfl_xor(m, d_));
    float qs = (m > 0.f) ? 127.f / m : 0.f;
    uint2 q;
    q.x = pack4(a.x, a.y, a.z, a.w, qs);
    q.y = pack4(b.x, b.y, b.z, b.w, qs);
    h0q[(size_t)row * 16 + lane] = q;
    if (lane == 0) sc0[row] = m * (1.f / 127.f);
}

// ---------- per-chunk bucket histogram -> C[c][b], super-bucket -> C2[c][s] ----------
__global__ __launch_bounds__(256) void k_count(const int* __restrict__ eu,
                                               const int* __restrict__ ei,
                                               int* __restrict__ C, int* __restrict__ C2,
                                               int E, int NB, int NS, int UA) {
    extern __shared__ int hist[];
    for (int k = threadIdx.x; k < NB; k += blockDim.x) hist[k] = 0;
    __syncthreads();
    int base = blockIdx.x * CHUNK;
    int n = min(CHUNK, E - base);
    for (int t = threadIdx.x; t < n; t += blockDim.x) {
        int u = ntload_i(eu + base + t);
        int i = ntload_i(ei + base + t);
        atomicAdd(&hist[u >> 6], 1);
        atomicAdd(&hist[(UA + i) >> 6], 1);
    }
    __syncthreads();
    int* Crow = C + (size_t)blockIdx.x * NB;
    for (int k = threadIdx.x; k < NB; k += blockDim.x) Crow[k] = hist[k];
    int* C2row = C2 + (size_t)blockIdx.x * NS;
    for (int s = threadIdx.x; s < NS; s += blockDim.x) {
        int b0 = s * 64, b1 = min(b0 + 64, NB);
        int acc = 0;
        for (int b = b0; b < b1; ++b) acc += hist[b];
        C2row[s] = acc;
    }
}

// ---------- tiled column scans over C (NC x NB) ----------
__global__ __launch_bounds__(256) void k_tile_sum(const int* __restrict__ C,
                                                  int* __restrict__ S, int NB, int NC) {
    int b = blockIdx.x * 256 + threadIdx.x;
    if (b >= NB) return;
    int tc = blockIdx.y;
    int c0 = tc * CTILE, c1 = min(c0 + CTILE, NC);
    int s = 0;
    for (int c = c0; c < c1; ++c) s += C[(size_t)c * NB + b];
    S[(size_t)tc * NB + b] = s;
}

__global__ __launch_bounds__(256) void k_super(int* __restrict__ S, int* __restrict__ T,
                                               int NB, int TC) {
    int b = blockIdx.x * 256 + threadIdx.x;
    if (b >= NB) return;
    int run = 0;
    for (int tc = 0; tc < TC; ++tc) {
        size_t k = (size_t)tc * NB + b;
        int v = S[k];
        S[k] = run;
        run += v;
    }
    T[b] = run;
}

__global__ __launch_bounds__(1024) void k_scan(const int* __restrict__ T,
                                               int* __restrict__ offb, int N) {
    __shared__ int partial[1024];
    int t = threadIdx.x;
    int CH = (N + 1023) >> 10;
    int c0 = min(t * CH, N), c1 = min(c0 + CH, N);
    int sum = 0;
    for (int k = c0; k < c1; ++k) sum += T[k];
    partial[t] = sum;
    __syncthreads();
    for (int s = 1; s < 1024; s <<= 1) {
        int add = (t >= s) ? partial[t - s] : 0;
        __syncthreads();
        partial[t] += add;
        __syncthreads();
    }
    int run = (t == 0) ? 0 : partial[t - 1];
    for (int k = c0; k < c1; ++k) { offb[k] = run; run += T[k]; }
    if (t == 0) offb[N] = partial[1023];
}

__global__ __launch_bounds__(256) void k_colscan(const int* __restrict__ C,
                                                 const int* __restrict__ S,
                                                 const int* __restrict__ offb,
                                                 int* __restrict__ colScan, int NB, int NC) {
    int b = blockIdx.x * 256 + threadIdx.x;
    if (b >= NB) return;
    int tc = blockIdx.y;
    int c0 = tc * CTILE, c1 = min(c0 + CTILE, NC);
    int run = offb[b] + S[(size_t)tc * NB + b];
    for (int c = c0; c < c1; ++c) {
        size_t k = (size_t)c * NB + b;
        colScan[k] = run;
        run += C[k];
    }
}

// ---------- pass 1: partition entries into super-buckets, chunk-local dense ----------
__global__ __launch_bounds__(256) void k_split(
    const int* __restrict__ eu, const int* __restrict__ ei, const float* __restrict__ w,
    const int* __restrict__ C2, int* __restrict__ P2, uint2* __restrict__ sbA,
    int E, int NC, int NS, int UA) {
    __shared__ int cur[64];
    __shared__ int tmp[64];
    int t = threadIdx.x;
    int c = blockIdx.x;
    if (c >= NC) return;
    if (t < NS) tmp[t] = C2[(size_t)c * NS + t];
    __syncthreads();
    if (t == 0) {
        int run = c * 2 * CHUNK;
        for (int s = 0; s < NS; ++s) {
            int v = tmp[s];
            cur[s] = run;
            P2[(size_t)c * NS + s] = run;
            run += v;
        }
    }
    __syncthreads();
    int base = c * CHUNK;
    int n = min(CHUNK, E - base);
    for (int k = t; k < n; k += 256) {
        int u  = ntload_i(eu + base + k);
        int gi = UA + ntload_i(ei + base + k);
        unsigned wb = __float_as_uint(ntload_f(w + base + k));
        int pu = atomicAdd(&cur[u >> 12], 1);
        sbA[pu] = make_uint2(((unsigned)(u & 4095) << 18) | (unsigned)gi, wb);
        int pi = atomicAdd(&cur[gi >> 12], 1);
        sbA[pi] = make_uint2(((unsigned)(gi & 4095) << 18) | (unsigned)u, wb);
    }
}

// ---------- pass 2: super-bucket runs -> final bucket-grouped positions ----------
__global__ __launch_bounds__(256) void k_sbscatter(
    const uint2* __restrict__ sbA, uint2* __restrict__ bkt,
    const int* __restrict__ C2, const int* __restrict__ P2,
    const int* __restrict__ colScan, int NB, int NC, int NS) {
    __shared__ int cur[64];
    int s = blockIdx.y;
    int j = blockIdx.x;
    int CL = (NC + NSPLIT - 1) / NSPLIT;
    int c0 = j * CL, c1 = min(NC, c0 + CL);
    if (c0 >= c1) return;
    int t = threadIdx.x;
    int b0 = s * 64;
    int nb = min(64, NB - b0);
    if (t < nb) cur[t] = colScan[(size_t)c0 * NB + b0 + t];
    __syncthreads();
    for (int c = c0; c < c1; ++c) {
        int start = P2[(size_t)c * NS + s];
        int len   = C2[(size_t)c * NS + s];
        for (int k = t; k < len; k += 256) {
            uint2 e = ntload_u2(sbA + start + k);
            int bl = (int)((e.x >> 24) & 63u);
            int p = atomicAdd(&cur[bl], 1);
            bkt[p] = e;
        }
    }
}

// ---------- per-bucket counting sort by row -> row-grouped u32 CSR + off[] ----
__device__ inline unsigned pack_entry(uint2 e) {
    float wv = __uint_as_float(e.y);
    int wq = __float2int_rn(wv * 16384.f);
    wq = min(wq, 16383);
    wq = max(wq, 0);
    return (e.x & 0x3FFFFu) | ((unsigned)wq << 18);
}

__global__ __launch_bounds__(256) void k_rowsort(
    const uint2* __restrict__ entA, unsigned* __restrict__ entB,
    const int* __restrict__ offb, int* __restrict__ off, int NP) {
    __shared__ int hist[64];
    __shared__ int rowOff[64];
    __shared__ int cursor[64];
    __shared__ uint2 ebuf[RS_CAP];
    int b = blockIdx.x, t = threadIdx.x;
    int segBase = offb[b];
    int len = offb[b + 1] - segBase;
    if (t < 64) hist[t] = 0;
    __syncthreads();
    bool inLds = (len <= RS_CAP);
    for (int k = t; k < len; k += 256) {
        uint2 e = ntload_u2(entA + segBase + k);
        if (inLds) ebuf[k] = e;
        atomicAdd(&hist[(e.x >> 18) & 63u], 1);
    }
    __syncthreads();
    if (t == 0) {
        int run = 0;
        for (int r = 0; r < 64; ++r) { rowOff[r] = run; cursor[r] = run; run += hist[r]; }
    }
    __syncthreads();
    if (inLds) {
        for (int k = t; k < len; k += 256) {
            uint2 e = ebuf[k];
            int p = atomicAdd(&cursor[(e.x >> 18) & 63u], 1);
            entB[segBase + p] = pack_entry(e);
        }
    } else {
        for (int k = t; k < len; k += 256) {
            uint2 e = ntload_u2(entA + segBase + k);
            int p = atomicAdd(&cursor[(e.x >> 18) & 63u], 1);
            entB[segBase + p] = pack_entry(e);
        }
    }
    __syncthreads();
    if (t < 64) {
        int g = b * 64 + t;
        if (g <= NP) off[g] = segBase + rowOff[t];
    }
}

// ---------- pull-SpMM on int8 sources (phase-split, 8-way unroll) ----------
// CSR entry: wq14 << 18 | src18. MODE 0: quantize -> nxtq + scn. MODE 1: epilogue.
#define WDEQ (1.f / 16384.f)
template <int MODE>
__global__ __launch_bounds__(TPB) void k_spmm(
    const uint2* __restrict__ q, const float* __restrict__ sc,
    uint2* __restrict__ nxtq, float* __restrict__ scn,
    const uint2* __restrict__ e1q, const float* __restrict__ sc1,
    const uint2* __restrict__ e2q, const float* __restrict__ sc2,
    const float* __restrict__ ue, const float* __restrict__ ie,
    float* __restrict__ out,
    const int* __restrict__ off, const unsigned* __restrict__ csr,
    int U, int UA, int rowBase, int rowCnt) {
    int row = rowBase + blockIdx.x * (TPB / 16) + (threadIdx.x >> 4);
    if (row >= rowBase + rowCnt) return;
    int lane = threadIdx.x & 15;
    int beg = off[row], end = off[row + 1];
    float4 sa = make_float4(0.f, 0.f, 0.f, 0.f);
    float4 sb = make_float4(0.f, 0.f, 0.f, 0.f);

    int p = beg;
    int n8 = (end - beg) >> 3;
    if (n8 > 0) {
        unsigned m0 = csr[p],     m1 = csr[p + 1], m2 = csr[p + 2], m3 = csr[p + 3];
        unsigned m4 = csr[p + 4], m5 = csr[p + 5], m6 = csr[p + 6], m7 = csr[p + 7];
        for (int it = 0; it < n8; ++it) {
            int s0 = m0 & SRCMASK, s1 = m1 & SRCMASK;
            int s2 = m2 & SRCMASK, s3 = m3 & SRCMASK;
            int s4 = m4 & SRCMASK, s5 = m5 & SRCMASK;
            int s6 = m6 & SRCMASK, s7 = m7 & SRCMASK;
            uint2 g0 = q[(size_t)s0 * 16 + lane];
            uint2 g1 = q[(size_t)s1 * 16 + lane];
            uint2 g2 = q[(size_t)s2 * 16 + lane];
            uint2 g3 = q[(size_t)s3 * 16 + lane];
            uint2 g4 = q[(size_t)s4 * 16 + lane];
            uint2 g5 = q[(size_t)s5 * 16 + lane];
            uint2 g6 = q[(size_t)s6 * 16 + lane];
            uint2 g7 = q[(size_t)s7 * 16 + lane];
            float f0 = (float)(m0 >> 18) * WDEQ * sc[s0];
            float f1 = (float)(m1 >> 18) * WDEQ * sc[s1];
            float f2 = (float)(m2 >> 18) * WDEQ * sc[s2];
            float f3 = (float)(m3 >> 18) * WDEQ * sc[s3];
            float f4 = (float)(m4 >> 18) * WDEQ * sc[s4];
            float f5 = (float)(m5 >> 18) * WDEQ * sc[s5];
            float f6 = (float)(m6 >> 18) * WDEQ * sc[s6];
            float f7 = (float)(m7 >> 18) * WDEQ * sc[s7];
            int pn = p + 8;
            if (it + 1 < n8) {
                m0 = csr[pn];     m1 = csr[pn + 1]; m2 = csr[pn + 2]; m3 = csr[pn + 3];
                m4 = csr[pn + 4]; m5 = csr[pn + 5]; m6 = csr[pn + 6]; m7 = csr[pn + 7];
            }
            acc_q8(sa, sb, g0, f0);
            acc_q8(sa, sb, g1, f1);
            acc_q8(sa, sb, g2, f2);
            acc_q8(sa, sb, g3, f3);
            acc_q8(sa, sb, g4, f4);
            acc_q8(sa, sb, g5, f5);
            acc_q8(sa, sb, g6, f6);
            acc_q8(sa, sb, g7, f7);
            p = pn;
        }
    }
    if (p + 4 <= end) {
        unsigned m0 = csr[p], m1 = csr[p + 1], m2 = csr[p + 2], m3 = csr[p + 3];
        int s0 = m0 & SRCMASK, s1 = m1 & SRCMASK;
        int s2 = m2 & SRCMASK, s3 = m3 & SRCMASK;
        uint2 g0 = q[(size_t)s0 * 16 + lane];
        uint2 g1 = q[(size_t)s1 * 16 + lane];
        uint2 g2 = q[(size_t)s2 * 16 + lane];
        uint2 g3 = q[(size_t)s3 * 16 + lane];
        acc_q8(sa, sb, g0, (float)(m0 >> 18) * WDEQ * sc[s0]);
        acc_q8(sa, sb, g1, (float)(m1 >> 18) * WDEQ * sc[s1]);
        acc_q8(sa, sb, g2, (float)(m2 >> 18) * WDEQ * sc[s2]);
        acc_q8(sa, sb, g3, (float)(m3 >> 18) * WDEQ * sc[s3]);
        p += 4;
    }
    for (; p < end; ++p) {
        unsigned m_ = csr[p];
        int s_ = m_ & SRCMASK;
        uint2 g_ = q[(size_t)s_ * 16 + lane];
        acc_q8(sa, sb, g_, (float)(m_ >> 18) * WDEQ * sc[s_]);
    }

    if (MODE == 0) {
        float m = fmaxf(fmaxf(fmaxf(fabsf(sa.x), fabsf(sa.y)), fmaxf(fabsf(sa.z), fabsf(sa.w))),
                        fmaxf(fmaxf(fabsf(sb.x), fabsf(sb.y)), fmaxf(fabsf(sb.z), fabsf(sb.w))));
        for (int d_ = 1; d_ < 16; d_ <<= 1) m = fmaxf(m, __shfl_xor(m, d_));
        float qs = (m > 0.f) ? 127.f / m : 0.f;
        uint2 qo;
        qo.x = pack4(sa.x, sa.y, sa.z, sa.w, qs);
        qo.y = pack4(sb.x, sb.y, sb.z, sb.w, qs);
        nxtq[(size_t)row * 16 + lane] = qo;   // re-read as gather source: cached
        if (lane == 0) scn[row] = m * (1.f / 127.f);
    } else {
        int outRow;
        const float* e0p;
        if (row < U)        { outRow = row;            e0p = ue + (size_t)row * D + lane * 8; }
        else if (row >= UA) { outRow = U + (row - UA); e0p = ie + (size_t)(row - UA) * D + lane * 8; }
        else return;  // pad row
        float4 e0a = ntload_f4(e0p);
        float4 e0b = ntload_f4(e0p + 4);
        uint2 q1 = e1q[(size_t)row * 16 + lane]; float s1r = sc1[row];
        uint2 q2 = e2q[(size_t)row * 16 + lane]; float s2r = sc2[row];
        unsigned x1 = q1.x, y1 = q1.y, x2 = q2.x, y2 = q2.y;
        float4 ra, rb;
        ra.x = 0.25f * (e0a.x + s1r * (float)((int)(x1 << 24) >> 24) + s2r * (float)((int)(x2 << 24) >> 24) + sa.x);
        ra.y = 0.25f * (e0a.y + s1r * (float)((int)(x1 << 16) >> 24) + s2r * (float)((int)(x2 << 16) >> 24) + sa.y);
        ra.z = 0.25f * (e0a.z + s1r * (float)((int)(x1 <<  8) >> 24) + s2r * (float)((int)(x2 <<  8) >> 24) + sa.z);
        ra.w = 0.25f * (e0a.w + s1r * (float)((int)(x1      ) >> 24) + s2r * (float)((int)(x2      ) >> 24) + sa.w);
        rb.x = 0.25f * (e0b.x + s1r * (float)((int)(y1 << 24) >> 24) + s2r * (float)((int)(y2 << 24) >> 24) + sb.x);
        rb.y = 0.25f * (e0b.y + s1r * (float)((int)(y1 << 16) >> 24) + s2r * (float)((int)(y2 << 16) >> 24) + sb.y);
        rb.z = 0.25f * (e0b.z + s1r * (float)((int)(y1 <<  8) >> 24) + s2r * (float)((int)(y2 <<  8) >> 24) + sb.z);
        rb.w = 0.25f * (e0b.w + s1r * (float)((int)(y1      ) >> 24) + s2r * (float)((int)(y2      ) >> 24) + sb.w);
        float* op = out + (size_t)outRow * D + lane * 8;
        ntstore_f4(op, ra);
        ntstore_f4(op + 4, rb);
    }
}

extern "C" void kernel_launch(void* const* d_in, const int* in_sizes, int n_in,
                              void* d_out, int out_size, void* d_ws, size_t ws_size,
                              hipStream_t stream) {
    const float* ue = (const float*)d_in[0];
    const float* ie = (const float*)d_in[1];
    const float* w  = (const float*)d_in[2];
    const int*   eu = (const int*)d_in[3];
    const int*   ei = (const int*)d_in[4];
    // n_layers fixed at 3 by the reference setup.

    const int U  = in_sizes[0] / D;
    const int I  = in_sizes[1] / D;
    const int E  = in_sizes[2];
    const int UA = ((U + 63) >> 6) << 6;
    const int NP = UA + I;
    const int NB = (NP + 63) >> 6;
    const int NS = (NP + 4095) >> 12;       // super-buckets (4096 rows)
    const int NC = (E + CHUNK - 1) / CHUNK;
    const int TC = (NC + CTILE - 1) / CTILE;
    const size_t nE2 = (size_t)2 * E;
    const size_t nX  = (size_t)NC * 2 * CHUNK;   // sbA region (>= nE2)

    if (NS > 64) return;  // geometry guard

    // ws: h0q | e1q | e2q | sc0..2 | X(sbA / u32 CSR) | Y(bkt) | C | colScan | S | T
    //     | offb | off | C2 | P2
    uint2* h0q = (uint2*)d_ws;
    uint2* e1q = h0q + (size_t)NP * 16;
    uint2* e2q = e1q + (size_t)NP * 16;
    float* sc0 = (float*)(e2q + (size_t)NP * 16);
    float* sc1 = sc0 + NP;
    float* sc2 = sc1 + NP;
    uint2* X   = (uint2*)(sc2 + NP);       // pass-1 out; rowsort writes u32 CSR here
    uint2* Y   = X + nX;                   // pass-2 out (bucket-grouped)
    int* C       = (int*)(Y + nE2);
    int* colScan = C + (size_t)NC * NB;
    int* S       = colScan + (size_t)NC * NB;
    int* T       = S + (size_t)TC * NB;
    int* offb    = T + NB;
    int* off     = offb + NB + 1;
    int* C2      = off + NP + 1;
    int* P2      = C2 + (size_t)NC * NS;

    const size_t needed = (size_t)NP * D * 3 + (size_t)NP * 12
                        + (nX + nE2) * 8
                        + ((size_t)2 * NC * NB + (size_t)TC * NB + NB + (NB + 1)
                           + (NP + 1) + (size_t)2 * NC * NS) * 4;
    if (ws_size < needed) return;

    const int nbR = (NP + 15) / 16;
    const int nbU = (UA + 15) / 16;
    const int nbI = (I + 15) / 16;
    const int TB = (NB + 255) / 256;

    k_quant8<<<nbR, TPB, 0, stream>>>(ue, ie, h0q, sc0, U, UA, NP);
    k_count<<<NC, 256, (size_t)NB * 4, stream>>>(eu, ei, C, C2, E, NB, NS, UA);
    k_tile_sum<<<dim3(TB, TC), 256, 0, stream>>>(C, S, NB, NC);
    k_super<<<TB, 256, 0, stream>>>(S, T, NB, TC);
    k_scan<<<1, 1024, 0, stream>>>(T, offb, NB);
    k_colscan<<<dim3(TB, TC), 256, 0, stream>>>(C, S, offb, colScan, NB, NC);
    k_split<<<NC, 256, 0, stream>>>(eu, ei, w, C2, P2, X, E, NC, NS, UA);
    k_sbscatter<<<dim3(NSPLIT, NS), 256, 0, stream>>>(X, Y, C2, P2, colScan, NB, NC, NS);
    k_rowsort<<<NB, 256, 0, stream>>>(Y, (unsigned*)X, offb, off, NP);

    const unsigned* csr = (const unsigned*)X;
    // layer 1
    k_spmm<0><<<nbU, TPB, 0, stream>>>(h0q, sc0, e1q, sc1, nullptr, nullptr, nullptr, nullptr,
                                       ue, ie, nullptr, off, csr, U, UA, 0, UA);
    k_spmm<0><<<nbI, TPB, 0, stream>>>(h0q, sc0, e1q, sc1, nullptr, nullptr, nullptr, nullptr,
                                       ue, ie, nullptr, off, csr, U, UA, UA, I);
    // layer 2
    k_spmm<0><<<nbU, TPB, 0, stream>>>(e1q, sc1, e2q, sc2, nullptr, nullptr, nullptr, nullptr,
                                       ue, ie, nullptr, off, csr, U, UA, 0, UA);
    k_spmm<0><<<nbI, TPB, 0, stream>>>(e1q, sc1, e2q, sc2, nullptr, nullptr, nullptr, nullptr,
                                       ue, ie, nullptr, off, csr, U, UA, UA, I);
    // layer 3 + fused epilogue
    k_spmm<1><<<nbU, TPB, 0, stream>>>(e2q, sc2, nullptr, nullptr, e1q, sc1, e2q, sc2,
                                       ue, ie, (float*)d_out, off, csr, U, UA, 0, UA);
    k_spmm<1><<<nbI, TPB, 0, stream>>>(e2q, sc2, nullptr, nullptr, e1q, sc1, e2q, sc2,
                                       ue, ie, (float*)d_out, off, csr, U, UA, UA, I);
}